// Round 6
// baseline (219.053 us; speedup 1.0000x reference)
//
#include <hip/hip_runtime.h>

typedef _Float16 h8 __attribute__((ext_vector_type(8)));
typedef _Float16 h4 __attribute__((ext_vector_type(4)));
typedef _Float16 h2 __attribute__((ext_vector_type(2)));

// Problem constants (reference: B,M,N,L,S,KERN = 4,256,256,24,22,256; KERN==M → tile is identity)
constexpr int B_ = 4, M_ = 256, N_ = 256, L_ = 24, S_ = 22;
constexpr int SP_  = 24;    // shots padded to 24 (2 zero rows) for clean s-quads
constexpr int AP_  = 257;   // A4 [s][n] row pitch in h4 units (odd -> b64 reads 2-way, free)
constexpr int XTP_ = 25;    // XT [n][l] row pitch in h4 cells (200B rows, 50-dword stride, 2-way free)
constexpr int NYR_ = 280;   // Y rows per (bp,sq) plane (279 used)

// LDS layout (bytes):
constexpr int A4_BYTES = SP_ * AP_ * 8;            // 49,344  A[s][n] h4 over c
constexpr int XT_BYTES = N_ * XTP_ * 8;            // 51,200  x[n][l] h4 over b
constexpr int Y_BYTES  = 2 * 6 * NYR_ * 16;        // 53,760  Y[bp][sq][n'] 16B cells (2 h4: b-even, b-odd)
constexpr int XT_OFF   = A4_BYTES;                 // 49,344
constexpr int Y_OFF    = A4_BYTES + XT_BYTES;      // 100,544 (16B-aligned)
constexpr int WMAX_OFF = Y_OFF + Y_BYTES;          // 154,304
constexpr int LDS_BYTES = WMAX_OFF + 32;           // 154,336 <= 163,840
constexpr int XT_OFF_H4 = XT_OFF / 8;              // 6,168
constexpr int Y_OFF_H4  = Y_OFF / 8;               // 12,568
constexpr int Y_OFF_H8  = Y_OFF / 16;              // 6,284

// Color bases as COMPILE-TIME constants (validated R6/R8/R9/R10):
constexpr float FR[L_] = {  // mu = 620
    6.252150e-05f, 1.904358e-04f, 5.418690e-04f, 1.440515e-03f, 3.577400e-03f,
    8.299750e-03f, 1.798893e-02f, 3.642490e-02f, 6.890060e-02f, 1.217600e-01f,
    2.010120e-01f, 3.100190e-01f, 4.466857e-01f, 6.012587e-01f, 7.560710e-01f,
    8.881955e-01f, 9.747661e-01f, 9.993953e-01f, 9.572367e-01f, 8.565352e-01f,
    7.160078e-01f, 5.591580e-01f, 4.079402e-01f, 2.780373e-01f};
constexpr float FG[L_] = {  // mu = 550
    1.110900e-02f, 2.348440e-02f, 4.638000e-02f, 8.557090e-02f, 1.474900e-01f,
    2.374920e-01f, 3.572560e-01f, 5.020580e-01f, 6.591400e-01f, 8.084270e-01f,
    9.262975e-01f, 9.915296e-01f, 9.915296e-01f, 9.262975e-01f, 8.084270e-01f,
    6.591400e-01f, 5.020580e-01f, 3.572560e-01f, 2.374920e-01f, 1.474900e-01f,
    8.557090e-02f, 4.638000e-02f, 2.348440e-02f, 1.110900e-02f};
constexpr float FB[L_] = {  // mu = 450 (pairs with wb)
    6.065307e-01f, 7.609727e-01f, 8.919300e-01f, 9.766475e-01f, 9.990553e-01f,
    9.547420e-01f, 8.523698e-01f, 7.109096e-01f, 5.539184e-01f, 4.032022e-01f,
    2.741855e-01f, 1.741852e-01f, 1.033776e-01f, 5.731640e-02f, 2.968800e-02f,
    1.436580e-02f, 6.494090e-03f, 2.742560e-03f, 1.079230e-03f, 3.988070e-04f,
    1.369660e-04f, 4.417250e-05f, 1.327420e-05f, 3.726650e-06f};
constexpr float FC[L_] = {  // mu = 500 (pairs with wc)
    1.353353e-01f, 2.204053e-01f, 3.353338e-01f, 4.766271e-01f, 6.328849e-01f,
    7.850828e-01f, 9.098110e-01f, 9.849909e-01f, 9.962264e-01f, 9.413024e-01f,
    8.308921e-01f, 6.851808e-01f, 5.278508e-01f, 3.798934e-01f, 2.554222e-01f,
    1.604349e-01f, 9.414200e-02f, 5.160780e-02f, 2.642960e-02f, 1.264440e-02f,
    5.651680e-03f, 2.359870e-03f, 9.205430e-04f, 3.354630e-04f};

__device__ __forceinline__ float fdot2(h2 a, h2 b, float c) {
    return __builtin_amdgcn_fdot2(a, b, c, false);
}

// Phase B l-half (verified correct in R14). Each half: 24 acc regs + <=12
// in-flight Y b128 loads -> ~90 peak live, far under any sane budget.
template<int LH>
__device__ __forceinline__ void phaseB_half(
    const h4* __restrict__ A4, const h8* __restrict__ Y8,
    float* __restrict__ out, const int tt, const int bp, const int m,
    float& vmax)
{
    float X0[12], X1[12];
    #pragma unroll
    for (int i = 0; i < 12; ++i) { X0[i] = 0.f; X1[i] = 0.f; }
    #pragma unroll 1
    for (int sq = 0; sq < 6; ++sq) {
        const int ab = (4 * sq) * AP_ + tt;
        const h4 q0 = A4[ab], q1 = A4[ab + AP_], q2 = A4[ab + 2 * AP_], q3 = A4[ab + 3 * AP_];
        const int ybase = (bp * 6 + sq) * NYR_ + tt;
        #pragma unroll
        for (int lo = 0; lo < 12; ++lo) {
            const int l = LH * 12 + lo;          // compile-time (lo unrolled)
            h2 f01; f01.x = (_Float16)FR[l]; f01.y = (_Float16)FG[l];
            h2 f23; f23.x = (_Float16)FB[l]; f23.y = (_Float16)FC[l];
            const float g0 = fdot2(h2{q0.x,q0.y}, f01, fdot2(h2{q0.z,q0.w}, f23, 0.f));
            const float g1 = fdot2(h2{q1.x,q1.y}, f01, fdot2(h2{q1.z,q1.w}, f23, 0.f));
            const float g2 = fdot2(h2{q2.x,q2.y}, f01, fdot2(h2{q2.z,q2.w}, f23, 0.f));
            const float g3 = fdot2(h2{q3.x,q3.y}, f01, fdot2(h2{q3.z,q3.w}, f23, 0.f));
            h2 G01; G01.x = (_Float16)g0; G01.y = (_Float16)g1;
            h2 G23; G23.x = (_Float16)g2; G23.y = (_Float16)g3;
            const h8 y = Y8[ybase + l];
            X0[lo] = fdot2(G01, h2{y[0],y[1]}, fdot2(G23, h2{y[2],y[3]}, X0[lo]));
            X1[lo] = fdot2(G01, h2{y[4],y[5]}, fdot2(G23, h2{y[6],y[7]}, X1[lo]));
        }
    }
    float4* o0 = reinterpret_cast<float4*>(out + (((2*bp    ) * M_ + m) * N_ + tt) * L_) + LH * 3;
    float4* o1 = reinterpret_cast<float4*>(out + (((2*bp + 1) * M_ + m) * N_ + tt) * L_) + LH * 3;
    #pragma unroll
    for (int i = 0; i < 3; ++i) {
        float4 v0, v1;
        v0.x = X0[4*i+0]; v0.y = X0[4*i+1]; v0.z = X0[4*i+2]; v0.w = X0[4*i+3];
        v1.x = X1[4*i+0]; v1.y = X1[4*i+1]; v1.z = X1[4*i+2]; v1.w = X1[4*i+3];
        vmax = fmaxf(vmax, fmaxf(fmaxf(v0.x, v0.y), fmaxf(v0.z, v0.w)));
        vmax = fmaxf(vmax, fmaxf(fmaxf(v1.x, v1.y), fmaxf(v1.z, v1.w)));
        o0[i] = v0;
        o1[i] = v1;
    }
}

// R16: R15 falsified the static-LDS theory (LDS_Block_Size now 154,624 but
// VGPR still pinned at 128, WRITE still ~126MB scratch). Attribute ladder so
// far: waves_per_eu(2,2) -> 128; launch_bounds(512,2) -> 128. The only
// proven-good spelling is R11's waves_per_eu(1,*) (gave VGPR=256 at 256thr).
// R16 uses min-only amdgpu_waves_per_eu(1) PLUS the direct lever
// amdgpu_num_vgpr(256) (explicit cap; 256 chosen so 512/256 = 2 waves/SIMD
// still fit, matching the LDS-imposed limit). Phase B stays split so true
// demand (~120-170) lands well under 256 and the scheduler can't balloon
// past the 2-waves/SIMD boundary.
__global__ __launch_bounds__(512)
__attribute__((amdgpu_waves_per_eu(1), amdgpu_num_vgpr(256)))
void cassi_fused(
    const float* __restrict__ x,
    const float* __restrict__ wr, const float* __restrict__ wg,
    const float* __restrict__ wb, const float* __restrict__ wc,
    float* __restrict__ out, float* __restrict__ bmax_out)
{
    __shared__ __align__(16) char lds_raw[LDS_BYTES];   // static: descriptor sees 154KB
    h4* A4  = reinterpret_cast<h4*>(lds_raw);
    h4* XT4 = reinterpret_cast<h4*>(lds_raw) + XT_OFF_H4;
    h4* Y4  = reinterpret_cast<h4*>(lds_raw) + Y_OFF_H4;
    h8* Y8  = reinterpret_cast<h8*>(lds_raw) + Y_OFF_H8;
    float* wmax = reinterpret_cast<float*>(lds_raw + WMAX_OFF);

    const int t  = threadIdx.x;
    const int tt = t & 255;        // column / lane-within-half
    const int th = t >> 8;         // half index (0 or 1)
    const int m  = blockIdx.x;

    // ---- Staging ----
    // zero A pad rows s=22,23 (2*257 = 514 h4): 512 threads cover 0..511,
    // lanes 0,1 also cover 512,513 (cell 512 IS read: s=23, n=255).
    {
        h4 z; z.x = z.y = z.z = z.w = (_Float16)0.f;
        A4[S_ * AP_ + t] = z;
        if (t < 2) A4[S_ * AP_ + 512 + t] = z;
    }
    if (th == 0) {
        // x: thread tt stages column n=tt for all 4 b -> XT[n][l] h4{b0..b3}
        const float4* xb0 = reinterpret_cast<const float4*>(x + ((0 * M_ + m) * N_ + tt) * L_);
        const float4* xb1 = reinterpret_cast<const float4*>(x + ((1 * M_ + m) * N_ + tt) * L_);
        const float4* xb2 = reinterpret_cast<const float4*>(x + ((2 * M_ + m) * N_ + tt) * L_);
        const float4* xb3 = reinterpret_cast<const float4*>(x + ((3 * M_ + m) * N_ + tt) * L_);
        #pragma unroll
        for (int i = 0; i < 6; ++i) {
            const float4 v0 = xb0[i], v1 = xb1[i], v2 = xb2[i], v3 = xb3[i];
            h4 c0; c0.x=(_Float16)v0.x; c0.y=(_Float16)v1.x; c0.z=(_Float16)v2.x; c0.w=(_Float16)v3.x;
            h4 c1; c1.x=(_Float16)v0.y; c1.y=(_Float16)v1.y; c1.z=(_Float16)v2.y; c1.w=(_Float16)v3.y;
            h4 c2; c2.x=(_Float16)v0.z; c2.y=(_Float16)v1.z; c2.z=(_Float16)v2.z; c2.w=(_Float16)v3.z;
            h4 c3; c3.x=(_Float16)v0.w; c3.y=(_Float16)v1.w; c3.z=(_Float16)v2.w; c3.w=(_Float16)v3.w;
            XT4[tt * XTP_ + 4 * i + 0] = c0;
            XT4[tt * XTP_ + 4 * i + 1] = c1;
            XT4[tt * XTP_ + 4 * i + 2] = c2;
            XT4[tt * XTP_ + 4 * i + 3] = c3;
        }
    } else {
        // weights: coalesced, normalized once, h4-packed A[s][n]
        const float* wrm = wr + m * (N_ * S_);
        const float* wgm = wg + m * (N_ * S_);
        const float* wbm = wb + m * (N_ * S_);
        const float* wcm = wc + m * (N_ * S_);
        #pragma unroll 1
        for (int i = 0; i < S_; ++i) {
            const int f = i * 256 + tt;
            const float r = wrm[f], g = wgm[f], u = wbm[f], v = wcm[f];
            const int n = f / S_, s = f - n * S_;
            const float inv = 1.f / (r + g + u + v);
            h4 p;
            p.x = (_Float16)(r * inv); p.y = (_Float16)(g * inv);
            p.z = (_Float16)(u * inv); p.w = (_Float16)(v * inv);
            A4[s * AP_ + n] = p;
        }
    }
    __syncthreads();

    // ---- Phase A: Y[b][n'][s-quad] gather. Half th handles sq = 3*th..3*th+2.
    // Waves 0 and 4 (tt < 64) run the dual main+tail version; the rest run the
    // lean version (idx = tt-l always valid since tt >= 64 > 23). Wave-uniform.
    const int sqb = th * 3;
    if (tt < 64) {
        #pragma unroll 1
        for (int sqo = 0; sqo < 3; ++sqo) {
            const int sq = sqb + sqo;
            float4 aM[4], aT[4];
            #pragma unroll
            for (int b = 0; b < 4; ++b) { aM[b].x=aM[b].y=aM[b].z=aM[b].w=0.f; aT[b]=aM[b]; }
            #pragma unroll
            for (int l = 0; l < L_; ++l) {
                h2 f01; f01.x = (_Float16)FR[l]; f01.y = (_Float16)FG[l];
                h2 f23; f23.x = (_Float16)FB[l]; f23.y = (_Float16)FC[l];
                const bool mn = (l <= tt);
                const int idx = mn ? (tt - l) : (256 + tt - l);
                const float mm = mn ? 1.f : 0.f;
                const int ab = (4 * sq) * AP_ + idx;
                const h4 p0 = A4[ab], p1 = A4[ab + AP_], p2 = A4[ab + 2 * AP_], p3 = A4[ab + 3 * AP_];
                const h4 xq = XT4[idx * XTP_ + l];
                const float g0 = fdot2(h2{p0.x,p0.y}, f01, fdot2(h2{p0.z,p0.w}, f23, 0.f));
                const float g1 = fdot2(h2{p1.x,p1.y}, f01, fdot2(h2{p1.z,p1.w}, f23, 0.f));
                const float g2 = fdot2(h2{p2.x,p2.y}, f01, fdot2(h2{p2.z,p2.w}, f23, 0.f));
                const float g3 = fdot2(h2{p3.x,p3.y}, f01, fdot2(h2{p3.z,p3.w}, f23, 0.f));
                const float gm0 = g0 * mm, gt0 = g0 - gm0;
                const float gm1 = g1 * mm, gt1 = g1 - gm1;
                const float gm2 = g2 * mm, gt2 = g2 - gm2;
                const float gm3 = g3 * mm, gt3 = g3 - gm3;
                const float xv[4] = {(float)xq.x, (float)xq.y, (float)xq.z, (float)xq.w};
                #pragma unroll
                for (int b = 0; b < 4; ++b) {
                    aM[b].x += gm0 * xv[b]; aT[b].x += gt0 * xv[b];
                    aM[b].y += gm1 * xv[b]; aT[b].y += gt1 * xv[b];
                    aM[b].z += gm2 * xv[b]; aT[b].z += gt2 * xv[b];
                    aM[b].w += gm3 * xv[b]; aT[b].w += gt3 * xv[b];
                }
            }
            #pragma unroll
            for (int b = 0; b < 4; ++b) {
                const int cell = ((b >> 1) * 6 + sq) * NYR_;
                h4 pm;
                pm.x=(_Float16)aM[b].x; pm.y=(_Float16)aM[b].y;
                pm.z=(_Float16)aM[b].z; pm.w=(_Float16)aM[b].w;
                Y4[(cell + tt) * 2 + (b & 1)] = pm;
                if (tt < 23) {
                    h4 pt;
                    pt.x=(_Float16)aT[b].x; pt.y=(_Float16)aT[b].y;
                    pt.z=(_Float16)aT[b].z; pt.w=(_Float16)aT[b].w;
                    Y4[(cell + 256 + tt) * 2 + (b & 1)] = pt;
                }
            }
        }
    } else {
        #pragma unroll 1
        for (int sqo = 0; sqo < 3; ++sqo) {
            const int sq = sqb + sqo;
            float4 aM[4];
            #pragma unroll
            for (int b = 0; b < 4; ++b) { aM[b].x=aM[b].y=aM[b].z=aM[b].w=0.f; }
            #pragma unroll
            for (int l = 0; l < L_; ++l) {
                h2 f01; f01.x = (_Float16)FR[l]; f01.y = (_Float16)FG[l];
                h2 f23; f23.x = (_Float16)FB[l]; f23.y = (_Float16)FC[l];
                const int idx = tt - l;      // tt >= 64 -> always >= 41
                const int ab = (4 * sq) * AP_ + idx;
                const h4 p0 = A4[ab], p1 = A4[ab + AP_], p2 = A4[ab + 2 * AP_], p3 = A4[ab + 3 * AP_];
                const h4 xq = XT4[idx * XTP_ + l];
                const float g0 = fdot2(h2{p0.x,p0.y}, f01, fdot2(h2{p0.z,p0.w}, f23, 0.f));
                const float g1 = fdot2(h2{p1.x,p1.y}, f01, fdot2(h2{p1.z,p1.w}, f23, 0.f));
                const float g2 = fdot2(h2{p2.x,p2.y}, f01, fdot2(h2{p2.z,p2.w}, f23, 0.f));
                const float g3 = fdot2(h2{p3.x,p3.y}, f01, fdot2(h2{p3.z,p3.w}, f23, 0.f));
                const float xv[4] = {(float)xq.x, (float)xq.y, (float)xq.z, (float)xq.w};
                #pragma unroll
                for (int b = 0; b < 4; ++b) {
                    aM[b].x += g0 * xv[b];
                    aM[b].y += g1 * xv[b];
                    aM[b].z += g2 * xv[b];
                    aM[b].w += g3 * xv[b];
                }
            }
            #pragma unroll
            for (int b = 0; b < 4; ++b) {
                const int cell = ((b >> 1) * 6 + sq) * NYR_;
                h4 pm;
                pm.x=(_Float16)aM[b].x; pm.y=(_Float16)aM[b].y;
                pm.z=(_Float16)aM[b].z; pm.w=(_Float16)aM[b].w;
                Y4[(cell + tt) * 2 + (b & 1)] = pm;
            }
        }
    }
    __syncthreads();

    // ---- Phase B: one b-pair per thread (bp = th), two l-halves.
    float vmax = 0.f;
    phaseB_half<0>(A4, Y8, out, tt, th, m, vmax);
    phaseB_half<1>(A4, Y8, out, tt, th, m, vmax);

    #pragma unroll
    for (int off = 32; off > 0; off >>= 1)
        vmax = fmaxf(vmax, __shfl_xor(vmax, off, 64));
    if ((t & 63) == 0) wmax[t >> 6] = vmax;
    __syncthreads();
    if (t == 0) {
        float v = wmax[0];
        #pragma unroll
        for (int w = 1; w < 8; ++w) v = fmaxf(v, wmax[w]);
        bmax_out[m] = v;
    }
}

// Normalize; each block re-reduces the 256 per-block maxes itself.
__global__ __launch_bounds__(256) void cassi_norm(float* __restrict__ out,
                                                  const float* __restrict__ bmax)
{
    __shared__ float wm[4];
    const int t = threadIdx.x;
    float v = bmax[t];
    #pragma unroll
    for (int off = 32; off > 0; off >>= 1)
        v = fmaxf(v, __shfl_xor(v, off, 64));
    if ((t & 63) == 0) wm[t >> 6] = v;
    __syncthreads();
    const float inv = 1.f / fmaxf(fmaxf(wm[0], wm[1]), fmaxf(wm[2], wm[3]));
    const int i = (blockIdx.x * 256 + t) * 4;
    float4 q = *reinterpret_cast<float4*>(out + i);
    q.x *= inv; q.y *= inv; q.z *= inv; q.w *= inv;
    *reinterpret_cast<float4*>(out + i) = q;
}

extern "C" void kernel_launch(void* const* d_in, const int* in_sizes, int n_in,
                              void* d_out, int out_size, void* d_ws, size_t ws_size,
                              hipStream_t stream) {
    const float* x  = (const float*)d_in[0];
    const float* wr = (const float*)d_in[1];
    const float* wg = (const float*)d_in[2];
    const float* wb = (const float*)d_in[3];
    const float* wc = (const float*)d_in[4];
    float* out  = (float*)d_out;
    float* bmax = (float*)d_ws;          // 256 per-block maxes

    cassi_fused<<<M_, 512, 0, stream>>>(x, wr, wg, wb, wc, out, bmax);
    const int n4blocks = (B_ * M_ * N_ * L_) / 4 / 256;     // 6144, exact
    cassi_norm<<<n4blocks, 256, 0, stream>>>(out, bmax);
}

// Round 7
// 198.208 us; speedup vs baseline: 1.1052x; 1.1052x over previous
//
#include <hip/hip_runtime.h>

typedef _Float16 h8 __attribute__((ext_vector_type(8)));
typedef _Float16 h4 __attribute__((ext_vector_type(4)));
typedef _Float16 h2 __attribute__((ext_vector_type(2)));

// Problem constants (reference: B,M,N,L,S,KERN = 4,256,256,24,22,256; KERN==M → tile is identity)
constexpr int B_ = 4, M_ = 256, N_ = 256, L_ = 24, S_ = 22;
constexpr int SP_  = 24;    // shots padded to 24 (2 zero rows) for clean s-quads
constexpr int AP_  = 257;   // A4 [s][n] row pitch in h4 units (odd -> b64 reads 2-way, free)
constexpr int XTP_ = 25;    // XT [n][l] row pitch in h4 cells (200B rows, 50-dword stride, 2-way free)
constexpr int NYR_ = 280;   // Y rows per (bp,sq) plane (279 used)

// LDS layout (bytes):
constexpr int A4_BYTES = SP_ * AP_ * 8;            // 49,344  A[s][n] h4 over c
constexpr int XT_BYTES = N_ * XTP_ * 8;            // 51,200  x[n][l] h4 over b
constexpr int Y_BYTES  = 2 * 6 * NYR_ * 16;        // 53,760  Y[bp][sq][n'] 16B cells (2 h4: b-even, b-odd)
constexpr int XT_OFF   = A4_BYTES;                 // 49,344
constexpr int Y_OFF    = A4_BYTES + XT_BYTES;      // 100,544 (16B-aligned)
constexpr int WMAX_OFF = Y_OFF + Y_BYTES;          // 154,304
constexpr int LDS_BYTES = WMAX_OFF + 32;           // 154,336 <= 163,840
constexpr int XT_OFF_H4 = XT_OFF / 8;              // 6,168
constexpr int Y_OFF_H4  = Y_OFF / 8;               // 12,568
constexpr int Y_OFF_H8  = Y_OFF / 16;              // 6,284

// Color bases as COMPILE-TIME constants (validated R6/R8/R9/R10):
constexpr float FR[L_] = {  // mu = 620
    6.252150e-05f, 1.904358e-04f, 5.418690e-04f, 1.440515e-03f, 3.577400e-03f,
    8.299750e-03f, 1.798893e-02f, 3.642490e-02f, 6.890060e-02f, 1.217600e-01f,
    2.010120e-01f, 3.100190e-01f, 4.466857e-01f, 6.012587e-01f, 7.560710e-01f,
    8.881955e-01f, 9.747661e-01f, 9.993953e-01f, 9.572367e-01f, 8.565352e-01f,
    7.160078e-01f, 5.591580e-01f, 4.079402e-01f, 2.780373e-01f};
constexpr float FG[L_] = {  // mu = 550
    1.110900e-02f, 2.348440e-02f, 4.638000e-02f, 8.557090e-02f, 1.474900e-01f,
    2.374920e-01f, 3.572560e-01f, 5.020580e-01f, 6.591400e-01f, 8.084270e-01f,
    9.262975e-01f, 9.915296e-01f, 9.915296e-01f, 9.262975e-01f, 8.084270e-01f,
    6.591400e-01f, 5.020580e-01f, 3.572560e-01f, 2.374920e-01f, 1.474900e-01f,
    8.557090e-02f, 4.638000e-02f, 2.348440e-02f, 1.110900e-02f};
constexpr float FB[L_] = {  // mu = 450 (pairs with wb)
    6.065307e-01f, 7.609727e-01f, 8.919300e-01f, 9.766475e-01f, 9.990553e-01f,
    9.547420e-01f, 8.523698e-01f, 7.109096e-01f, 5.539184e-01f, 4.032022e-01f,
    2.741855e-01f, 1.741852e-01f, 1.033776e-01f, 5.731640e-02f, 2.968800e-02f,
    1.436580e-02f, 6.494090e-03f, 2.742560e-03f, 1.079230e-03f, 3.988070e-04f,
    1.369660e-04f, 4.417250e-05f, 1.327420e-05f, 3.726650e-06f};
constexpr float FC[L_] = {  // mu = 500 (pairs with wc)
    1.353353e-01f, 2.204053e-01f, 3.353338e-01f, 4.766271e-01f, 6.328849e-01f,
    7.850828e-01f, 9.098110e-01f, 9.849909e-01f, 9.962264e-01f, 9.413024e-01f,
    8.308921e-01f, 6.851808e-01f, 5.278508e-01f, 3.798934e-01f, 2.554222e-01f,
    1.604349e-01f, 9.414200e-02f, 5.160780e-02f, 2.642960e-02f, 1.264440e-02f,
    5.651680e-03f, 2.359870e-03f, 9.205430e-04f, 3.354630e-04f};

__device__ __forceinline__ float fdot2(h2 a, h2 b, float c) {
    return __builtin_amdgcn_fdot2(a, b, c, false);
}

// Phase B l-half (verified correct in R14). Each half: 24 acc regs + <=12
// in-flight Y b128 loads -> ~90 peak live, fits the 128 cap.
template<int LH>
__device__ __forceinline__ void phaseB_half(
    const h4* __restrict__ A4, const h8* __restrict__ Y8,
    float* __restrict__ out, const int tt, const int bp, const int m,
    float& vmax)
{
    float X0[12], X1[12];
    #pragma unroll
    for (int i = 0; i < 12; ++i) { X0[i] = 0.f; X1[i] = 0.f; }
    #pragma unroll 1
    for (int sq = 0; sq < 6; ++sq) {
        const int ab = (4 * sq) * AP_ + tt;
        const h4 q0 = A4[ab], q1 = A4[ab + AP_], q2 = A4[ab + 2 * AP_], q3 = A4[ab + 3 * AP_];
        const int ybase = (bp * 6 + sq) * NYR_ + tt;
        #pragma unroll
        for (int lo = 0; lo < 12; ++lo) {
            const int l = LH * 12 + lo;          // compile-time (lo unrolled)
            h2 f01; f01.x = (_Float16)FR[l]; f01.y = (_Float16)FG[l];
            h2 f23; f23.x = (_Float16)FB[l]; f23.y = (_Float16)FC[l];
            const float g0 = fdot2(h2{q0.x,q0.y}, f01, fdot2(h2{q0.z,q0.w}, f23, 0.f));
            const float g1 = fdot2(h2{q1.x,q1.y}, f01, fdot2(h2{q1.z,q1.w}, f23, 0.f));
            const float g2 = fdot2(h2{q2.x,q2.y}, f01, fdot2(h2{q2.z,q2.w}, f23, 0.f));
            const float g3 = fdot2(h2{q3.x,q3.y}, f01, fdot2(h2{q3.z,q3.w}, f23, 0.f));
            h2 G01; G01.x = (_Float16)g0; G01.y = (_Float16)g1;
            h2 G23; G23.x = (_Float16)g2; G23.y = (_Float16)g3;
            const h8 y = Y8[ybase + l];
            X0[lo] = fdot2(G01, h2{y[0],y[1]}, fdot2(G23, h2{y[2],y[3]}, X0[lo]));
            X1[lo] = fdot2(G01, h2{y[4],y[5]}, fdot2(G23, h2{y[6],y[7]}, X1[lo]));
        }
    }
    float4* o0 = reinterpret_cast<float4*>(out + (((2*bp    ) * M_ + m) * N_ + tt) * L_) + LH * 3;
    float4* o1 = reinterpret_cast<float4*>(out + (((2*bp + 1) * M_ + m) * N_ + tt) * L_) + LH * 3;
    #pragma unroll
    for (int i = 0; i < 3; ++i) {
        float4 v0, v1;
        v0.x = X0[4*i+0]; v0.y = X0[4*i+1]; v0.z = X0[4*i+2]; v0.w = X0[4*i+3];
        v1.x = X1[4*i+0]; v1.y = X1[4*i+1]; v1.z = X1[4*i+2]; v1.w = X1[4*i+3];
        vmax = fmaxf(vmax, fmaxf(fmaxf(v0.x, v0.y), fmaxf(v0.z, v0.w)));
        vmax = fmaxf(vmax, fmaxf(fmaxf(v1.x, v1.y), fmaxf(v1.z, v1.w)));
        o0[i] = v0;
        o1[i] = v1;
    }
}

// R17: attribute route falsified 3x (waves_per_eu(2,2) / launch_bounds(512,2)
// / num_vgpr(256) -> VGPR pinned 128). Accept the 128 cap; eliminate the
// spill instead. Evidence the spiller is phase A: WRITE excess (~100MB) is
// invariant under every phase-B restructure. Mechanism: the fully-unrolled
// l-loop exposes 24 iterations x 10 VGPRs of ds_read results; the scheduler
// batch-hoists them past the 128 cap -> scratch. Fix: sched_barrier(0) every
// 6 unrolled iterations caps in-flight loads at ~60 regs (+32 acc ~ fits).
// Constants stay compile-time literals; phase B keeps the R14 split.
__global__ __launch_bounds__(512)
void cassi_fused(
    const float* __restrict__ x,
    const float* __restrict__ wr, const float* __restrict__ wg,
    const float* __restrict__ wb, const float* __restrict__ wc,
    float* __restrict__ out, float* __restrict__ bmax_out)
{
    __shared__ __align__(16) char lds_raw[LDS_BYTES];   // static descriptor: 154KB
    h4* A4  = reinterpret_cast<h4*>(lds_raw);
    h4* XT4 = reinterpret_cast<h4*>(lds_raw) + XT_OFF_H4;
    h4* Y4  = reinterpret_cast<h4*>(lds_raw) + Y_OFF_H4;
    h8* Y8  = reinterpret_cast<h8*>(lds_raw) + Y_OFF_H8;
    float* wmax = reinterpret_cast<float*>(lds_raw + WMAX_OFF);

    const int t  = threadIdx.x;
    const int tt = t & 255;        // column / lane-within-half
    const int th = t >> 8;         // half index (0 or 1)
    const int m  = blockIdx.x;

    // ---- Staging ----
    // zero A pad rows s=22,23 (2*257 = 514 h4): 512 threads cover 0..511,
    // lanes 0,1 also cover 512,513 (cell 512 IS read: s=23, n=255).
    {
        h4 z; z.x = z.y = z.z = z.w = (_Float16)0.f;
        A4[S_ * AP_ + t] = z;
        if (t < 2) A4[S_ * AP_ + 512 + t] = z;
    }
    if (th == 0) {
        // x: thread tt stages column n=tt for all 4 b -> XT[n][l] h4{b0..b3}
        const float4* xb0 = reinterpret_cast<const float4*>(x + ((0 * M_ + m) * N_ + tt) * L_);
        const float4* xb1 = reinterpret_cast<const float4*>(x + ((1 * M_ + m) * N_ + tt) * L_);
        const float4* xb2 = reinterpret_cast<const float4*>(x + ((2 * M_ + m) * N_ + tt) * L_);
        const float4* xb3 = reinterpret_cast<const float4*>(x + ((3 * M_ + m) * N_ + tt) * L_);
        #pragma unroll
        for (int i = 0; i < 6; ++i) {
            const float4 v0 = xb0[i], v1 = xb1[i], v2 = xb2[i], v3 = xb3[i];
            h4 c0; c0.x=(_Float16)v0.x; c0.y=(_Float16)v1.x; c0.z=(_Float16)v2.x; c0.w=(_Float16)v3.x;
            h4 c1; c1.x=(_Float16)v0.y; c1.y=(_Float16)v1.y; c1.z=(_Float16)v2.y; c1.w=(_Float16)v3.y;
            h4 c2; c2.x=(_Float16)v0.z; c2.y=(_Float16)v1.z; c2.z=(_Float16)v2.z; c2.w=(_Float16)v3.z;
            h4 c3; c3.x=(_Float16)v0.w; c3.y=(_Float16)v1.w; c3.z=(_Float16)v2.w; c3.w=(_Float16)v3.w;
            XT4[tt * XTP_ + 4 * i + 0] = c0;
            XT4[tt * XTP_ + 4 * i + 1] = c1;
            XT4[tt * XTP_ + 4 * i + 2] = c2;
            XT4[tt * XTP_ + 4 * i + 3] = c3;
        }
    } else {
        // weights: coalesced, normalized once, h4-packed A[s][n]
        const float* wrm = wr + m * (N_ * S_);
        const float* wgm = wg + m * (N_ * S_);
        const float* wbm = wb + m * (N_ * S_);
        const float* wcm = wc + m * (N_ * S_);
        #pragma unroll 1
        for (int i = 0; i < S_; ++i) {
            const int f = i * 256 + tt;
            const float r = wrm[f], g = wgm[f], u = wbm[f], v = wcm[f];
            const int n = f / S_, s = f - n * S_;
            const float inv = 1.f / (r + g + u + v);
            h4 p;
            p.x = (_Float16)(r * inv); p.y = (_Float16)(g * inv);
            p.z = (_Float16)(u * inv); p.w = (_Float16)(v * inv);
            A4[s * AP_ + n] = p;
        }
    }
    __syncthreads();

    // ---- Phase A: Y[b][n'][s-quad] gather. Half th handles sq = 3*th..3*th+2.
    // Waves 0 and 4 (tt < 64) run the dual main+tail version; the rest run the
    // lean version (idx = tt-l always valid since tt >= 64 > 23). Wave-uniform.
    // sched_barrier(0) every 6 unrolled l-iters caps in-flight ds_reads (~60
    // VGPRs) so the 128-cap allocator doesn't spill the accumulators.
    const int sqb = th * 3;
    if (tt < 64) {
        #pragma unroll 1
        for (int sqo = 0; sqo < 3; ++sqo) {
            const int sq = sqb + sqo;
            float4 aM[4], aT[4];
            #pragma unroll
            for (int b = 0; b < 4; ++b) { aM[b].x=aM[b].y=aM[b].z=aM[b].w=0.f; aT[b]=aM[b]; }
            #pragma unroll
            for (int l = 0; l < L_; ++l) {
                h2 f01; f01.x = (_Float16)FR[l]; f01.y = (_Float16)FG[l];
                h2 f23; f23.x = (_Float16)FB[l]; f23.y = (_Float16)FC[l];
                const bool mn = (l <= tt);
                const int idx = mn ? (tt - l) : (256 + tt - l);
                const float mm = mn ? 1.f : 0.f;
                const int ab = (4 * sq) * AP_ + idx;
                const h4 p0 = A4[ab], p1 = A4[ab + AP_], p2 = A4[ab + 2 * AP_], p3 = A4[ab + 3 * AP_];
                const h4 xq = XT4[idx * XTP_ + l];
                const float g0 = fdot2(h2{p0.x,p0.y}, f01, fdot2(h2{p0.z,p0.w}, f23, 0.f));
                const float g1 = fdot2(h2{p1.x,p1.y}, f01, fdot2(h2{p1.z,p1.w}, f23, 0.f));
                const float g2 = fdot2(h2{p2.x,p2.y}, f01, fdot2(h2{p2.z,p2.w}, f23, 0.f));
                const float g3 = fdot2(h2{p3.x,p3.y}, f01, fdot2(h2{p3.z,p3.w}, f23, 0.f));
                const float gm0 = g0 * mm, gt0 = g0 - gm0;
                const float gm1 = g1 * mm, gt1 = g1 - gm1;
                const float gm2 = g2 * mm, gt2 = g2 - gm2;
                const float gm3 = g3 * mm, gt3 = g3 - gm3;
                const float xv[4] = {(float)xq.x, (float)xq.y, (float)xq.z, (float)xq.w};
                #pragma unroll
                for (int b = 0; b < 4; ++b) {
                    aM[b].x += gm0 * xv[b]; aT[b].x += gt0 * xv[b];
                    aM[b].y += gm1 * xv[b]; aT[b].y += gt1 * xv[b];
                    aM[b].z += gm2 * xv[b]; aT[b].z += gt2 * xv[b];
                    aM[b].w += gm3 * xv[b]; aT[b].w += gt3 * xv[b];
                }
                if ((l % 6) == 5) __builtin_amdgcn_sched_barrier(0);
            }
            #pragma unroll
            for (int b = 0; b < 4; ++b) {
                const int cell = ((b >> 1) * 6 + sq) * NYR_;
                h4 pm;
                pm.x=(_Float16)aM[b].x; pm.y=(_Float16)aM[b].y;
                pm.z=(_Float16)aM[b].z; pm.w=(_Float16)aM[b].w;
                Y4[(cell + tt) * 2 + (b & 1)] = pm;
                if (tt < 23) {
                    h4 pt;
                    pt.x=(_Float16)aT[b].x; pt.y=(_Float16)aT[b].y;
                    pt.z=(_Float16)aT[b].z; pt.w=(_Float16)aT[b].w;
                    Y4[(cell + 256 + tt) * 2 + (b & 1)] = pt;
                }
            }
        }
    } else {
        #pragma unroll 1
        for (int sqo = 0; sqo < 3; ++sqo) {
            const int sq = sqb + sqo;
            float4 aM[4];
            #pragma unroll
            for (int b = 0; b < 4; ++b) { aM[b].x=aM[b].y=aM[b].z=aM[b].w=0.f; }
            #pragma unroll
            for (int l = 0; l < L_; ++l) {
                h2 f01; f01.x = (_Float16)FR[l]; f01.y = (_Float16)FG[l];
                h2 f23; f23.x = (_Float16)FB[l]; f23.y = (_Float16)FC[l];
                const int idx = tt - l;      // tt >= 64 -> always >= 41
                const int ab = (4 * sq) * AP_ + idx;
                const h4 p0 = A4[ab], p1 = A4[ab + AP_], p2 = A4[ab + 2 * AP_], p3 = A4[ab + 3 * AP_];
                const h4 xq = XT4[idx * XTP_ + l];
                const float g0 = fdot2(h2{p0.x,p0.y}, f01, fdot2(h2{p0.z,p0.w}, f23, 0.f));
                const float g1 = fdot2(h2{p1.x,p1.y}, f01, fdot2(h2{p1.z,p1.w}, f23, 0.f));
                const float g2 = fdot2(h2{p2.x,p2.y}, f01, fdot2(h2{p2.z,p2.w}, f23, 0.f));
                const float g3 = fdot2(h2{p3.x,p3.y}, f01, fdot2(h2{p3.z,p3.w}, f23, 0.f));
                const float xv[4] = {(float)xq.x, (float)xq.y, (float)xq.z, (float)xq.w};
                #pragma unroll
                for (int b = 0; b < 4; ++b) {
                    aM[b].x += g0 * xv[b];
                    aM[b].y += g1 * xv[b];
                    aM[b].z += g2 * xv[b];
                    aM[b].w += g3 * xv[b];
                }
                if ((l % 6) == 5) __builtin_amdgcn_sched_barrier(0);
            }
            #pragma unroll
            for (int b = 0; b < 4; ++b) {
                const int cell = ((b >> 1) * 6 + sq) * NYR_;
                h4 pm;
                pm.x=(_Float16)aM[b].x; pm.y=(_Float16)aM[b].y;
                pm.z=(_Float16)aM[b].z; pm.w=(_Float16)aM[b].w;
                Y4[(cell + tt) * 2 + (b & 1)] = pm;
            }
        }
    }
    __syncthreads();

    // ---- Phase B: one b-pair per thread (bp = th), two l-halves.
    float vmax = 0.f;
    phaseB_half<0>(A4, Y8, out, tt, th, m, vmax);
    phaseB_half<1>(A4, Y8, out, tt, th, m, vmax);

    #pragma unroll
    for (int off = 32; off > 0; off >>= 1)
        vmax = fmaxf(vmax, __shfl_xor(vmax, off, 64));
    if ((t & 63) == 0) wmax[t >> 6] = vmax;
    __syncthreads();
    if (t == 0) {
        float v = wmax[0];
        #pragma unroll
        for (int w = 1; w < 8; ++w) v = fmaxf(v, wmax[w]);
        bmax_out[m] = v;
    }
}

// Normalize; each block re-reduces the 256 per-block maxes itself.
__global__ __launch_bounds__(256) void cassi_norm(float* __restrict__ out,
                                                  const float* __restrict__ bmax)
{
    __shared__ float wm[4];
    const int t = threadIdx.x;
    float v = bmax[t];
    #pragma unroll
    for (int off = 32; off > 0; off >>= 1)
        v = fmaxf(v, __shfl_xor(v, off, 64));
    if ((t & 63) == 0) wm[t >> 6] = v;
    __syncthreads();
    const float inv = 1.f / fmaxf(fmaxf(wm[0], wm[1]), fmaxf(wm[2], wm[3]));
    const int i = (blockIdx.x * 256 + t) * 4;
    float4 q = *reinterpret_cast<float4*>(out + i);
    q.x *= inv; q.y *= inv; q.z *= inv; q.w *= inv;
    *reinterpret_cast<float4*>(out + i) = q;
}

extern "C" void kernel_launch(void* const* d_in, const int* in_sizes, int n_in,
                              void* d_out, int out_size, void* d_ws, size_t ws_size,
                              hipStream_t stream) {
    const float* x  = (const float*)d_in[0];
    const float* wr = (const float*)d_in[1];
    const float* wg = (const float*)d_in[2];
    const float* wb = (const float*)d_in[3];
    const float* wc = (const float*)d_in[4];
    float* out  = (float*)d_out;
    float* bmax = (float*)d_ws;          // 256 per-block maxes

    cassi_fused<<<M_, 512, 0, stream>>>(x, wr, wg, wb, wc, out, bmax);
    const int n4blocks = (B_ * M_ * N_ * L_) / 4 / 256;     // 6144, exact
    cassi_norm<<<n4blocks, 256, 0, stream>>>(out, bmax);
}

// Round 8
// 197.711 us; speedup vs baseline: 1.1079x; 1.0025x over previous
//
#include <hip/hip_runtime.h>

typedef _Float16 h8 __attribute__((ext_vector_type(8)));
typedef _Float16 h4 __attribute__((ext_vector_type(4)));
typedef _Float16 h2 __attribute__((ext_vector_type(2)));

// Problem constants (reference: B,M,N,L,S,KERN = 4,256,256,24,22,256; KERN==M → tile is identity)
constexpr int B_ = 4, M_ = 256, N_ = 256, L_ = 24, S_ = 22;
constexpr int SP_  = 24;    // shots padded to 24 (2 zero rows) for clean s-quads
constexpr int AP_  = 257;   // A4 [s][n] row pitch in h4 units (odd -> b64 reads 2-way, free)
constexpr int XTP_ = 25;    // XT [n][l] row pitch in h4 cells (200B rows, 50-dword stride, 2-way free)
constexpr int NYR_ = 280;   // Y rows per (bp,sq) plane (279 used)

// LDS layout (bytes):
constexpr int A4_BYTES = SP_ * AP_ * 8;            // 49,344  A[s][n] h4 over c
constexpr int XT_BYTES = N_ * XTP_ * 8;            // 51,200  x[n][l] h4 over b
constexpr int Y_BYTES  = 2 * 6 * NYR_ * 16;        // 53,760  Y[bp][sq][n'] 16B cells (2 h4: b-even, b-odd)
constexpr int XT_OFF   = A4_BYTES;                 // 49,344
constexpr int Y_OFF    = A4_BYTES + XT_BYTES;      // 100,544 (16B-aligned)
constexpr int WMAX_OFF = Y_OFF + Y_BYTES;          // 154,304
constexpr int LDS_BYTES = WMAX_OFF + 32;           // 154,336 <= 163,840
constexpr int XT_OFF_H4 = XT_OFF / 8;              // 6,168
constexpr int Y_OFF_H4  = Y_OFF / 8;               // 12,568
constexpr int Y_OFF_H8  = Y_OFF / 16;              // 6,284

// Color bases as COMPILE-TIME constants (validated R6/R8/R9/R10):
constexpr float FR[L_] = {  // mu = 620
    6.252150e-05f, 1.904358e-04f, 5.418690e-04f, 1.440515e-03f, 3.577400e-03f,
    8.299750e-03f, 1.798893e-02f, 3.642490e-02f, 6.890060e-02f, 1.217600e-01f,
    2.010120e-01f, 3.100190e-01f, 4.466857e-01f, 6.012587e-01f, 7.560710e-01f,
    8.881955e-01f, 9.747661e-01f, 9.993953e-01f, 9.572367e-01f, 8.565352e-01f,
    7.160078e-01f, 5.591580e-01f, 4.079402e-01f, 2.780373e-01f};
constexpr float FG[L_] = {  // mu = 550
    1.110900e-02f, 2.348440e-02f, 4.638000e-02f, 8.557090e-02f, 1.474900e-01f,
    2.374920e-01f, 3.572560e-01f, 5.020580e-01f, 6.591400e-01f, 8.084270e-01f,
    9.262975e-01f, 9.915296e-01f, 9.915296e-01f, 9.262975e-01f, 8.084270e-01f,
    6.591400e-01f, 5.020580e-01f, 3.572560e-01f, 2.374920e-01f, 1.474900e-01f,
    8.557090e-02f, 4.638000e-02f, 2.348440e-02f, 1.110900e-02f};
constexpr float FB[L_] = {  // mu = 450 (pairs with wb)
    6.065307e-01f, 7.609727e-01f, 8.919300e-01f, 9.766475e-01f, 9.990553e-01f,
    9.547420e-01f, 8.523698e-01f, 7.109096e-01f, 5.539184e-01f, 4.032022e-01f,
    2.741855e-01f, 1.741852e-01f, 1.033776e-01f, 5.731640e-02f, 2.968800e-02f,
    1.436580e-02f, 6.494090e-03f, 2.742560e-03f, 1.079230e-03f, 3.988070e-04f,
    1.369660e-04f, 4.417250e-05f, 1.327420e-05f, 3.726650e-06f};
constexpr float FC[L_] = {  // mu = 500 (pairs with wc)
    1.353353e-01f, 2.204053e-01f, 3.353338e-01f, 4.766271e-01f, 6.328849e-01f,
    7.850828e-01f, 9.098110e-01f, 9.849909e-01f, 9.962264e-01f, 9.413024e-01f,
    8.308921e-01f, 6.851808e-01f, 5.278508e-01f, 3.798934e-01f, 2.554222e-01f,
    1.604349e-01f, 9.414200e-02f, 5.160780e-02f, 2.642960e-02f, 1.264440e-02f,
    5.651680e-03f, 2.359870e-03f, 9.205430e-04f, 3.354630e-04f};

__device__ __forceinline__ float fdot2(h2 a, h2 b, float c) {
    return __builtin_amdgcn_fdot2(a, b, c, false);
}

// Phase B l-half (verified correct in R14). sched_barrier every 4 lo-iters
// caps in-flight Y8 loads at ~16 regs (+24 acc) under the 128-VGPR cap.
template<int LH>
__device__ __forceinline__ void phaseB_half(
    const h4* __restrict__ A4, const h8* __restrict__ Y8,
    float* __restrict__ out, const int tt, const int bp, const int m,
    float& vmax)
{
    float X0[12], X1[12];
    #pragma unroll
    for (int i = 0; i < 12; ++i) { X0[i] = 0.f; X1[i] = 0.f; }
    #pragma unroll 1
    for (int sq = 0; sq < 6; ++sq) {
        const int ab = (4 * sq) * AP_ + tt;
        const h4 q0 = A4[ab], q1 = A4[ab + AP_], q2 = A4[ab + 2 * AP_], q3 = A4[ab + 3 * AP_];
        const int ybase = (bp * 6 + sq) * NYR_ + tt;
        #pragma unroll
        for (int lo = 0; lo < 12; ++lo) {
            const int l = LH * 12 + lo;          // compile-time (lo unrolled)
            h2 f01; f01.x = (_Float16)FR[l]; f01.y = (_Float16)FG[l];
            h2 f23; f23.x = (_Float16)FB[l]; f23.y = (_Float16)FC[l];
            const float g0 = fdot2(h2{q0.x,q0.y}, f01, fdot2(h2{q0.z,q0.w}, f23, 0.f));
            const float g1 = fdot2(h2{q1.x,q1.y}, f01, fdot2(h2{q1.z,q1.w}, f23, 0.f));
            const float g2 = fdot2(h2{q2.x,q2.y}, f01, fdot2(h2{q2.z,q2.w}, f23, 0.f));
            const float g3 = fdot2(h2{q3.x,q3.y}, f01, fdot2(h2{q3.z,q3.w}, f23, 0.f));
            h2 G01; G01.x = (_Float16)g0; G01.y = (_Float16)g1;
            h2 G23; G23.x = (_Float16)g2; G23.y = (_Float16)g3;
            const h8 y = Y8[ybase + l];
            X0[lo] = fdot2(G01, h2{y[0],y[1]}, fdot2(G23, h2{y[2],y[3]}, X0[lo]));
            X1[lo] = fdot2(G01, h2{y[4],y[5]}, fdot2(G23, h2{y[6],y[7]}, X1[lo]));
            if ((lo & 3) == 3) __builtin_amdgcn_sched_barrier(0);
        }
    }
    float4* o0 = reinterpret_cast<float4*>(out + (((2*bp    ) * M_ + m) * N_ + tt) * L_) + LH * 3;
    float4* o1 = reinterpret_cast<float4*>(out + (((2*bp + 1) * M_ + m) * N_ + tt) * L_) + LH * 3;
    #pragma unroll
    for (int i = 0; i < 3; ++i) {
        float4 v0, v1;
        v0.x = X0[4*i+0]; v0.y = X0[4*i+1]; v0.z = X0[4*i+2]; v0.w = X0[4*i+3];
        v1.x = X1[4*i+0]; v1.y = X1[4*i+1]; v1.z = X1[4*i+2]; v1.w = X1[4*i+3];
        vmax = fmaxf(vmax, fmaxf(fmaxf(v0.x, v0.y), fmaxf(v0.z, v0.w)));
        vmax = fmaxf(vmax, fmaxf(fmaxf(v1.x, v1.y), fmaxf(v1.z, v1.w)));
        o0[i] = v0;
        o1[i] = v1;
    }
}

// R18: R17 validated the hoist-spill mechanism (chunk=6: WRITE 126->109MB,
// FETCH 58->47MB=clean, dur 130->112). Dose was too small: 60 regs of
// in-flight ds_reads + 32 acc + staging's 24 hoisted float4 globals (96
// regs!) still bust the 128 cap. R18 pins ALL THREE hoist sites harder:
// phase A chunk=3 (30 regs), x-staging chunk=1 i-iter (16 regs), phase B
// chunk=4 lo-iters (16 regs). Predicted: WRITE < 60MB, dur ~90-100.
__global__ __launch_bounds__(512)
void cassi_fused(
    const float* __restrict__ x,
    const float* __restrict__ wr, const float* __restrict__ wg,
    const float* __restrict__ wb, const float* __restrict__ wc,
    float* __restrict__ out, float* __restrict__ bmax_out)
{
    __shared__ __align__(16) char lds_raw[LDS_BYTES];   // static descriptor: 154KB
    h4* A4  = reinterpret_cast<h4*>(lds_raw);
    h4* XT4 = reinterpret_cast<h4*>(lds_raw) + XT_OFF_H4;
    h4* Y4  = reinterpret_cast<h4*>(lds_raw) + Y_OFF_H4;
    h8* Y8  = reinterpret_cast<h8*>(lds_raw) + Y_OFF_H8;
    float* wmax = reinterpret_cast<float*>(lds_raw + WMAX_OFF);

    const int t  = threadIdx.x;
    const int tt = t & 255;        // column / lane-within-half
    const int th = t >> 8;         // half index (0 or 1)
    const int m  = blockIdx.x;

    // ---- Staging ----
    // zero A pad rows s=22,23 (2*257 = 514 h4): 512 threads cover 0..511,
    // lanes 0,1 also cover 512,513 (cell 512 IS read: s=23, n=255).
    {
        h4 z; z.x = z.y = z.z = z.w = (_Float16)0.f;
        A4[S_ * AP_ + t] = z;
        if (t < 2) A4[S_ * AP_ + 512 + t] = z;
    }
    if (th == 0) {
        // x: thread tt stages column n=tt for all 4 b -> XT[n][l] h4{b0..b3}.
        // sched_barrier per i-iter: only 4 float4 loads (16 regs) in flight.
        const float4* xb0 = reinterpret_cast<const float4*>(x + ((0 * M_ + m) * N_ + tt) * L_);
        const float4* xb1 = reinterpret_cast<const float4*>(x + ((1 * M_ + m) * N_ + tt) * L_);
        const float4* xb2 = reinterpret_cast<const float4*>(x + ((2 * M_ + m) * N_ + tt) * L_);
        const float4* xb3 = reinterpret_cast<const float4*>(x + ((3 * M_ + m) * N_ + tt) * L_);
        #pragma unroll
        for (int i = 0; i < 6; ++i) {
            const float4 v0 = xb0[i], v1 = xb1[i], v2 = xb2[i], v3 = xb3[i];
            h4 c0; c0.x=(_Float16)v0.x; c0.y=(_Float16)v1.x; c0.z=(_Float16)v2.x; c0.w=(_Float16)v3.x;
            h4 c1; c1.x=(_Float16)v0.y; c1.y=(_Float16)v1.y; c1.z=(_Float16)v2.y; c1.w=(_Float16)v3.y;
            h4 c2; c2.x=(_Float16)v0.z; c2.y=(_Float16)v1.z; c2.z=(_Float16)v2.z; c2.w=(_Float16)v3.z;
            h4 c3; c3.x=(_Float16)v0.w; c3.y=(_Float16)v1.w; c3.z=(_Float16)v2.w; c3.w=(_Float16)v3.w;
            XT4[tt * XTP_ + 4 * i + 0] = c0;
            XT4[tt * XTP_ + 4 * i + 1] = c1;
            XT4[tt * XTP_ + 4 * i + 2] = c2;
            XT4[tt * XTP_ + 4 * i + 3] = c3;
            __builtin_amdgcn_sched_barrier(0);
        }
    } else {
        // weights: coalesced, normalized once, h4-packed A[s][n]
        const float* wrm = wr + m * (N_ * S_);
        const float* wgm = wg + m * (N_ * S_);
        const float* wbm = wb + m * (N_ * S_);
        const float* wcm = wc + m * (N_ * S_);
        #pragma unroll 1
        for (int i = 0; i < S_; ++i) {
            const int f = i * 256 + tt;
            const float r = wrm[f], g = wgm[f], u = wbm[f], v = wcm[f];
            const int n = f / S_, s = f - n * S_;
            const float inv = 1.f / (r + g + u + v);
            h4 p;
            p.x = (_Float16)(r * inv); p.y = (_Float16)(g * inv);
            p.z = (_Float16)(u * inv); p.w = (_Float16)(v * inv);
            A4[s * AP_ + n] = p;
        }
    }
    __syncthreads();

    // ---- Phase A: Y[b][n'][s-quad] gather. Half th handles sq = 3*th..3*th+2.
    // Waves 0 and 4 (tt < 64) run the dual main+tail version; the rest run the
    // lean version (idx = tt-l always valid since tt >= 64 > 23). Wave-uniform.
    // sched_barrier(0) every 3 unrolled l-iters caps in-flight ds_reads (~30
    // VGPRs) so the 128-cap allocator doesn't spill the accumulators.
    const int sqb = th * 3;
    if (tt < 64) {
        #pragma unroll 1
        for (int sqo = 0; sqo < 3; ++sqo) {
            const int sq = sqb + sqo;
            float4 aM[4], aT[4];
            #pragma unroll
            for (int b = 0; b < 4; ++b) { aM[b].x=aM[b].y=aM[b].z=aM[b].w=0.f; aT[b]=aM[b]; }
            #pragma unroll
            for (int l = 0; l < L_; ++l) {
                h2 f01; f01.x = (_Float16)FR[l]; f01.y = (_Float16)FG[l];
                h2 f23; f23.x = (_Float16)FB[l]; f23.y = (_Float16)FC[l];
                const bool mn = (l <= tt);
                const int idx = mn ? (tt - l) : (256 + tt - l);
                const float mm = mn ? 1.f : 0.f;
                const int ab = (4 * sq) * AP_ + idx;
                const h4 p0 = A4[ab], p1 = A4[ab + AP_], p2 = A4[ab + 2 * AP_], p3 = A4[ab + 3 * AP_];
                const h4 xq = XT4[idx * XTP_ + l];
                const float g0 = fdot2(h2{p0.x,p0.y}, f01, fdot2(h2{p0.z,p0.w}, f23, 0.f));
                const float g1 = fdot2(h2{p1.x,p1.y}, f01, fdot2(h2{p1.z,p1.w}, f23, 0.f));
                const float g2 = fdot2(h2{p2.x,p2.y}, f01, fdot2(h2{p2.z,p2.w}, f23, 0.f));
                const float g3 = fdot2(h2{p3.x,p3.y}, f01, fdot2(h2{p3.z,p3.w}, f23, 0.f));
                const float gm0 = g0 * mm, gt0 = g0 - gm0;
                const float gm1 = g1 * mm, gt1 = g1 - gm1;
                const float gm2 = g2 * mm, gt2 = g2 - gm2;
                const float gm3 = g3 * mm, gt3 = g3 - gm3;
                const float xv[4] = {(float)xq.x, (float)xq.y, (float)xq.z, (float)xq.w};
                #pragma unroll
                for (int b = 0; b < 4; ++b) {
                    aM[b].x += gm0 * xv[b]; aT[b].x += gt0 * xv[b];
                    aM[b].y += gm1 * xv[b]; aT[b].y += gt1 * xv[b];
                    aM[b].z += gm2 * xv[b]; aT[b].z += gt2 * xv[b];
                    aM[b].w += gm3 * xv[b]; aT[b].w += gt3 * xv[b];
                }
                if ((l % 3) == 2) __builtin_amdgcn_sched_barrier(0);
            }
            #pragma unroll
            for (int b = 0; b < 4; ++b) {
                const int cell = ((b >> 1) * 6 + sq) * NYR_;
                h4 pm;
                pm.x=(_Float16)aM[b].x; pm.y=(_Float16)aM[b].y;
                pm.z=(_Float16)aM[b].z; pm.w=(_Float16)aM[b].w;
                Y4[(cell + tt) * 2 + (b & 1)] = pm;
                if (tt < 23) {
                    h4 pt;
                    pt.x=(_Float16)aT[b].x; pt.y=(_Float16)aT[b].y;
                    pt.z=(_Float16)aT[b].z; pt.w=(_Float16)aT[b].w;
                    Y4[(cell + 256 + tt) * 2 + (b & 1)] = pt;
                }
            }
        }
    } else {
        #pragma unroll 1
        for (int sqo = 0; sqo < 3; ++sqo) {
            const int sq = sqb + sqo;
            float4 aM[4];
            #pragma unroll
            for (int b = 0; b < 4; ++b) { aM[b].x=aM[b].y=aM[b].z=aM[b].w=0.f; }
            #pragma unroll
            for (int l = 0; l < L_; ++l) {
                h2 f01; f01.x = (_Float16)FR[l]; f01.y = (_Float16)FG[l];
                h2 f23; f23.x = (_Float16)FB[l]; f23.y = (_Float16)FC[l];
                const int idx = tt - l;      // tt >= 64 -> always >= 41
                const int ab = (4 * sq) * AP_ + idx;
                const h4 p0 = A4[ab], p1 = A4[ab + AP_], p2 = A4[ab + 2 * AP_], p3 = A4[ab + 3 * AP_];
                const h4 xq = XT4[idx * XTP_ + l];
                const float g0 = fdot2(h2{p0.x,p0.y}, f01, fdot2(h2{p0.z,p0.w}, f23, 0.f));
                const float g1 = fdot2(h2{p1.x,p1.y}, f01, fdot2(h2{p1.z,p1.w}, f23, 0.f));
                const float g2 = fdot2(h2{p2.x,p2.y}, f01, fdot2(h2{p2.z,p2.w}, f23, 0.f));
                const float g3 = fdot2(h2{p3.x,p3.y}, f01, fdot2(h2{p3.z,p3.w}, f23, 0.f));
                const float xv[4] = {(float)xq.x, (float)xq.y, (float)xq.z, (float)xq.w};
                #pragma unroll
                for (int b = 0; b < 4; ++b) {
                    aM[b].x += g0 * xv[b];
                    aM[b].y += g1 * xv[b];
                    aM[b].z += g2 * xv[b];
                    aM[b].w += g3 * xv[b];
                }
                if ((l % 3) == 2) __builtin_amdgcn_sched_barrier(0);
            }
            #pragma unroll
            for (int b = 0; b < 4; ++b) {
                const int cell = ((b >> 1) * 6 + sq) * NYR_;
                h4 pm;
                pm.x=(_Float16)aM[b].x; pm.y=(_Float16)aM[b].y;
                pm.z=(_Float16)aM[b].z; pm.w=(_Float16)aM[b].w;
                Y4[(cell + tt) * 2 + (b & 1)] = pm;
            }
        }
    }
    __syncthreads();

    // ---- Phase B: one b-pair per thread (bp = th), two l-halves.
    float vmax = 0.f;
    phaseB_half<0>(A4, Y8, out, tt, th, m, vmax);
    phaseB_half<1>(A4, Y8, out, tt, th, m, vmax);

    #pragma unroll
    for (int off = 32; off > 0; off >>= 1)
        vmax = fmaxf(vmax, __shfl_xor(vmax, off, 64));
    if ((t & 63) == 0) wmax[t >> 6] = vmax;
    __syncthreads();
    if (t == 0) {
        float v = wmax[0];
        #pragma unroll
        for (int w = 1; w < 8; ++w) v = fmaxf(v, wmax[w]);
        bmax_out[m] = v;
    }
}

// Normalize; each block re-reduces the 256 per-block maxes itself.
__global__ __launch_bounds__(256) void cassi_norm(float* __restrict__ out,
                                                  const float* __restrict__ bmax)
{
    __shared__ float wm[4];
    const int t = threadIdx.x;
    float v = bmax[t];
    #pragma unroll
    for (int off = 32; off > 0; off >>= 1)
        v = fmaxf(v, __shfl_xor(v, off, 64));
    if ((t & 63) == 0) wm[t >> 6] = v;
    __syncthreads();
    const float inv = 1.f / fmaxf(fmaxf(wm[0], wm[1]), fmaxf(wm[2], wm[3]));
    const int i = (blockIdx.x * 256 + t) * 4;
    float4 q = *reinterpret_cast<float4*>(out + i);
    q.x *= inv; q.y *= inv; q.z *= inv; q.w *= inv;
    *reinterpret_cast<float4*>(out + i) = q;
}

extern "C" void kernel_launch(void* const* d_in, const int* in_sizes, int n_in,
                              void* d_out, int out_size, void* d_ws, size_t ws_size,
                              hipStream_t stream) {
    const float* x  = (const float*)d_in[0];
    const float* wr = (const float*)d_in[1];
    const float* wg = (const float*)d_in[2];
    const float* wb = (const float*)d_in[3];
    const float* wc = (const float*)d_in[4];
    float* out  = (float*)d_out;
    float* bmax = (float*)d_ws;          // 256 per-block maxes

    cassi_fused<<<M_, 512, 0, stream>>>(x, wr, wg, wb, wc, out, bmax);
    const int n4blocks = (B_ * M_ * N_ * L_) / 4 / 256;     // 6144, exact
    cassi_norm<<<n4blocks, 256, 0, stream>>>(out, bmax);
}

// Round 9
// 182.966 us; speedup vs baseline: 1.1972x; 1.0806x over previous
//
#include <hip/hip_runtime.h>

typedef _Float16 h8 __attribute__((ext_vector_type(8)));
typedef _Float16 h4 __attribute__((ext_vector_type(4)));
typedef _Float16 h2 __attribute__((ext_vector_type(2)));

// Problem constants (reference: B,M,N,L,S,KERN = 4,256,256,24,22,256; KERN==M → tile is identity)
constexpr int B_ = 4, M_ = 256, N_ = 256, L_ = 24, S_ = 22;
constexpr int SP_  = 24;    // shots padded to 24 (2 zero rows) for clean s-quads
constexpr int AP_  = 257;   // A4 [s][n] row pitch in h4 units (odd -> b64 reads 2-way, free)
constexpr int XTP_ = 25;    // XT [n][l] row pitch in h4 cells (200B rows, 50-dword stride, 2-way free)
constexpr int NYR_ = 280;   // Y rows per (bp,sq) plane (279 used)

// LDS layout (bytes):
constexpr int A4_BYTES = SP_ * AP_ * 8;            // 49,344  A[s][n] h4 over c
constexpr int XT_BYTES = N_ * XTP_ * 8;            // 51,200  x[n][l] h4 over b
constexpr int Y_BYTES  = 2 * 6 * NYR_ * 16;        // 53,760  Y[bp][sq][n'] 16B cells (2 h4: b-even, b-odd)
constexpr int XT_OFF   = A4_BYTES;                 // 49,344
constexpr int Y_OFF    = A4_BYTES + XT_BYTES;      // 100,544 (16B-aligned)
constexpr int WMAX_OFF = Y_OFF + Y_BYTES;          // 154,304
constexpr int LDS_BYTES = WMAX_OFF + 32;           // 154,336 <= 163,840
constexpr int XT_OFF_H4 = XT_OFF / 8;              // 6,168
constexpr int XT_OFF_H2 = XT_OFF / 4;              // 12,336 (h2 view)
constexpr int Y_OFF_H4  = Y_OFF / 8;               // 12,568
constexpr int Y_OFF_H8  = Y_OFF / 16;              // 6,284

// Color bases as COMPILE-TIME constants (validated R6/R8/R9/R10):
constexpr float FR[L_] = {  // mu = 620
    6.252150e-05f, 1.904358e-04f, 5.418690e-04f, 1.440515e-03f, 3.577400e-03f,
    8.299750e-03f, 1.798893e-02f, 3.642490e-02f, 6.890060e-02f, 1.217600e-01f,
    2.010120e-01f, 3.100190e-01f, 4.466857e-01f, 6.012587e-01f, 7.560710e-01f,
    8.881955e-01f, 9.747661e-01f, 9.993953e-01f, 9.572367e-01f, 8.565352e-01f,
    7.160078e-01f, 5.591580e-01f, 4.079402e-01f, 2.780373e-01f};
constexpr float FG[L_] = {  // mu = 550
    1.110900e-02f, 2.348440e-02f, 4.638000e-02f, 8.557090e-02f, 1.474900e-01f,
    2.374920e-01f, 3.572560e-01f, 5.020580e-01f, 6.591400e-01f, 8.084270e-01f,
    9.262975e-01f, 9.915296e-01f, 9.915296e-01f, 9.262975e-01f, 8.084270e-01f,
    6.591400e-01f, 5.020580e-01f, 3.572560e-01f, 2.374920e-01f, 1.474900e-01f,
    8.557090e-02f, 4.638000e-02f, 2.348440e-02f, 1.110900e-02f};
constexpr float FB[L_] = {  // mu = 450 (pairs with wb)
    6.065307e-01f, 7.609727e-01f, 8.919300e-01f, 9.766475e-01f, 9.990553e-01f,
    9.547420e-01f, 8.523698e-01f, 7.109096e-01f, 5.539184e-01f, 4.032022e-01f,
    2.741855e-01f, 1.741852e-01f, 1.033776e-01f, 5.731640e-02f, 2.968800e-02f,
    1.436580e-02f, 6.494090e-03f, 2.742560e-03f, 1.079230e-03f, 3.988070e-04f,
    1.369660e-04f, 4.417250e-05f, 1.327420e-05f, 3.726650e-06f};
constexpr float FC[L_] = {  // mu = 500 (pairs with wc)
    1.353353e-01f, 2.204053e-01f, 3.353338e-01f, 4.766271e-01f, 6.328849e-01f,
    7.850828e-01f, 9.098110e-01f, 9.849909e-01f, 9.962264e-01f, 9.413024e-01f,
    8.308921e-01f, 6.851808e-01f, 5.278508e-01f, 3.798934e-01f, 2.554222e-01f,
    1.604349e-01f, 9.414200e-02f, 5.160780e-02f, 2.642960e-02f, 1.264440e-02f,
    5.651680e-03f, 2.359870e-03f, 9.205430e-04f, 3.354630e-04f};

__device__ __forceinline__ float fdot2(h2 a, h2 b, float c) {
    return __builtin_amdgcn_fdot2(a, b, c, false);
}

// Phase B l-half (verified correct in R14). sched_barrier every 4 lo-iters
// caps in-flight Y8 loads at ~16 regs (+24 acc) under the 128-VGPR cap.
template<int LH>
__device__ __forceinline__ void phaseB_half(
    const h4* __restrict__ A4, const h8* __restrict__ Y8,
    float* __restrict__ out, const int tt, const int bp, const int m,
    float& vmax)
{
    float X0[12], X1[12];
    #pragma unroll
    for (int i = 0; i < 12; ++i) { X0[i] = 0.f; X1[i] = 0.f; }
    #pragma unroll 1
    for (int sq = 0; sq < 6; ++sq) {
        const int ab = (4 * sq) * AP_ + tt;
        const h4 q0 = A4[ab], q1 = A4[ab + AP_], q2 = A4[ab + 2 * AP_], q3 = A4[ab + 3 * AP_];
        const int ybase = (bp * 6 + sq) * NYR_ + tt;
        #pragma unroll
        for (int lo = 0; lo < 12; ++lo) {
            const int l = LH * 12 + lo;          // compile-time (lo unrolled)
            h2 f01; f01.x = (_Float16)FR[l]; f01.y = (_Float16)FG[l];
            h2 f23; f23.x = (_Float16)FB[l]; f23.y = (_Float16)FC[l];
            const float g0 = fdot2(h2{q0.x,q0.y}, f01, fdot2(h2{q0.z,q0.w}, f23, 0.f));
            const float g1 = fdot2(h2{q1.x,q1.y}, f01, fdot2(h2{q1.z,q1.w}, f23, 0.f));
            const float g2 = fdot2(h2{q2.x,q2.y}, f01, fdot2(h2{q2.z,q2.w}, f23, 0.f));
            const float g3 = fdot2(h2{q3.x,q3.y}, f01, fdot2(h2{q3.z,q3.w}, f23, 0.f));
            h2 G01; G01.x = (_Float16)g0; G01.y = (_Float16)g1;
            h2 G23; G23.x = (_Float16)g2; G23.y = (_Float16)g3;
            const h8 y = Y8[ybase + l];
            X0[lo] = fdot2(G01, h2{y[0],y[1]}, fdot2(G23, h2{y[2],y[3]}, X0[lo]));
            X1[lo] = fdot2(G01, h2{y[4],y[5]}, fdot2(G23, h2{y[6],y[7]}, X1[lo]));
            if ((lo & 3) == 3) __builtin_amdgcn_sched_barrier(0);
        }
    }
    float4* o0 = reinterpret_cast<float4*>(out + (((2*bp    ) * M_ + m) * N_ + tt) * L_) + LH * 3;
    float4* o1 = reinterpret_cast<float4*>(out + (((2*bp + 1) * M_ + m) * N_ + tt) * L_) + LH * 3;
    #pragma unroll
    for (int i = 0; i < 3; ++i) {
        float4 v0, v1;
        v0.x = X0[4*i+0]; v0.y = X0[4*i+1]; v0.z = X0[4*i+2]; v0.w = X0[4*i+3];
        v1.x = X1[4*i+0]; v1.y = X1[4*i+1]; v1.z = X1[4*i+2]; v1.w = X1[4*i+3];
        vmax = fmaxf(vmax, fmaxf(fmaxf(v0.x, v0.y), fmaxf(v0.z, v0.w)));
        vmax = fmaxf(vmax, fmaxf(fmaxf(v1.x, v1.y), fmaxf(v1.z, v1.w)));
        o0[i] = v0;
        o1[i] = v1;
    }
}

// R19: R18 exhausted the hoist-spill theory (tripled barrier density; WRITE
// unchanged at ~110MB). Revised mechanism: the phase-A STEADY-STATE live set
// (32 acc + 10 loads + ~27 temps/addr + compiler baseline) doesn't fit 128,
// so the acc arrays spill/fill across the sq loop regardless of scheduling
// fences. Fix: bp-split phase A — each thread handles its half's b-pair
// (bp = th) for ALL 6 sq. Acc 32->16 regs, xq h4->h2 (one dword). Cost:
// G recomputed by both halves (+576 fdot2/thread, ~0.5us at 16% VALUBusy)
// and A-quad LDS reads double (~4us of LDS BW). Peak live ~86 -> fits 128.
// Phase B + staging unchanged from R18.
__global__ __launch_bounds__(512)
void cassi_fused(
    const float* __restrict__ x,
    const float* __restrict__ wr, const float* __restrict__ wg,
    const float* __restrict__ wb, const float* __restrict__ wc,
    float* __restrict__ out, float* __restrict__ bmax_out)
{
    __shared__ __align__(16) char lds_raw[LDS_BYTES];   // static descriptor: 154KB
    h4* A4  = reinterpret_cast<h4*>(lds_raw);
    h4* XT4 = reinterpret_cast<h4*>(lds_raw) + XT_OFF_H4;
    h2* XT2 = reinterpret_cast<h2*>(lds_raw) + XT_OFF_H2;
    h4* Y4  = reinterpret_cast<h4*>(lds_raw) + Y_OFF_H4;
    h8* Y8  = reinterpret_cast<h8*>(lds_raw) + Y_OFF_H8;
    float* wmax = reinterpret_cast<float*>(lds_raw + WMAX_OFF);

    const int t  = threadIdx.x;
    const int tt = t & 255;        // column / lane-within-half
    const int th = t >> 8;         // half index (0 or 1) == b-pair
    const int m  = blockIdx.x;

    // ---- Staging ----
    // zero A pad rows s=22,23 (2*257 = 514 h4): 512 threads cover 0..511,
    // lanes 0,1 also cover 512,513 (cell 512 IS read: s=23, n=255).
    {
        h4 z; z.x = z.y = z.z = z.w = (_Float16)0.f;
        A4[S_ * AP_ + t] = z;
        if (t < 2) A4[S_ * AP_ + 512 + t] = z;
    }
    if (th == 0) {
        // x: thread tt stages column n=tt for all 4 b -> XT[n][l] h4{b0..b3}.
        // sched_barrier per i-iter: only 4 float4 loads (16 regs) in flight.
        const float4* xb0 = reinterpret_cast<const float4*>(x + ((0 * M_ + m) * N_ + tt) * L_);
        const float4* xb1 = reinterpret_cast<const float4*>(x + ((1 * M_ + m) * N_ + tt) * L_);
        const float4* xb2 = reinterpret_cast<const float4*>(x + ((2 * M_ + m) * N_ + tt) * L_);
        const float4* xb3 = reinterpret_cast<const float4*>(x + ((3 * M_ + m) * N_ + tt) * L_);
        #pragma unroll
        for (int i = 0; i < 6; ++i) {
            const float4 v0 = xb0[i], v1 = xb1[i], v2 = xb2[i], v3 = xb3[i];
            h4 c0; c0.x=(_Float16)v0.x; c0.y=(_Float16)v1.x; c0.z=(_Float16)v2.x; c0.w=(_Float16)v3.x;
            h4 c1; c1.x=(_Float16)v0.y; c1.y=(_Float16)v1.y; c1.z=(_Float16)v2.y; c1.w=(_Float16)v3.y;
            h4 c2; c2.x=(_Float16)v0.z; c2.y=(_Float16)v1.z; c2.z=(_Float16)v2.z; c2.w=(_Float16)v3.z;
            h4 c3; c3.x=(_Float16)v0.w; c3.y=(_Float16)v1.w; c3.z=(_Float16)v2.w; c3.w=(_Float16)v3.w;
            XT4[tt * XTP_ + 4 * i + 0] = c0;
            XT4[tt * XTP_ + 4 * i + 1] = c1;
            XT4[tt * XTP_ + 4 * i + 2] = c2;
            XT4[tt * XTP_ + 4 * i + 3] = c3;
            __builtin_amdgcn_sched_barrier(0);
        }
    } else {
        // weights: coalesced, normalized once, h4-packed A[s][n]
        const float* wrm = wr + m * (N_ * S_);
        const float* wgm = wg + m * (N_ * S_);
        const float* wbm = wb + m * (N_ * S_);
        const float* wcm = wc + m * (N_ * S_);
        #pragma unroll 1
        for (int i = 0; i < S_; ++i) {
            const int f = i * 256 + tt;
            const float r = wrm[f], g = wgm[f], u = wbm[f], v = wcm[f];
            const int n = f / S_, s = f - n * S_;
            const float inv = 1.f / (r + g + u + v);
            h4 p;
            p.x = (_Float16)(r * inv); p.y = (_Float16)(g * inv);
            p.z = (_Float16)(u * inv); p.w = (_Float16)(v * inv);
            A4[s * AP_ + n] = p;
        }
    }
    __syncthreads();

    // ---- Phase A (bp-split): thread (tt,th) gathers Y for b-pair th, all 6
    // sq. Acc = 16 regs max (aM0,aM1 + aT0,aT1 on tail waves). Waves 0 and 4
    // (tt < 64) run the dual main+tail version; the rest run the lean version
    // (idx = tt-l always valid since tt >= 64 > 23). Wave-uniform branch.
    {
        const int bp = th;
        if (tt < 64) {
            #pragma unroll 1
            for (int sq = 0; sq < 6; ++sq) {
                float4 aM0, aM1, aT0, aT1;
                aM0.x=aM0.y=aM0.z=aM0.w=0.f; aM1=aM0; aT0=aM0; aT1=aM0;
                #pragma unroll
                for (int l = 0; l < L_; ++l) {
                    h2 f01; f01.x = (_Float16)FR[l]; f01.y = (_Float16)FG[l];
                    h2 f23; f23.x = (_Float16)FB[l]; f23.y = (_Float16)FC[l];
                    const bool mn = (l <= tt);
                    const int idx = mn ? (tt - l) : (256 + tt - l);
                    const float mm = mn ? 1.f : 0.f;
                    const int ab = (4 * sq) * AP_ + idx;
                    const h4 p0 = A4[ab], p1 = A4[ab + AP_], p2 = A4[ab + 2 * AP_], p3 = A4[ab + 3 * AP_];
                    const h2 xq = XT2[(idx * XTP_ + l) * 2 + bp];
                    const float g0 = fdot2(h2{p0.x,p0.y}, f01, fdot2(h2{p0.z,p0.w}, f23, 0.f));
                    const float g1 = fdot2(h2{p1.x,p1.y}, f01, fdot2(h2{p1.z,p1.w}, f23, 0.f));
                    const float g2 = fdot2(h2{p2.x,p2.y}, f01, fdot2(h2{p2.z,p2.w}, f23, 0.f));
                    const float g3 = fdot2(h2{p3.x,p3.y}, f01, fdot2(h2{p3.z,p3.w}, f23, 0.f));
                    const float gm0 = g0 * mm, gt0 = g0 - gm0;
                    const float gm1 = g1 * mm, gt1 = g1 - gm1;
                    const float gm2 = g2 * mm, gt2 = g2 - gm2;
                    const float gm3 = g3 * mm, gt3 = g3 - gm3;
                    const float xv0 = (float)xq.x, xv1 = (float)xq.y;
                    aM0.x += gm0 * xv0; aT0.x += gt0 * xv0;
                    aM0.y += gm1 * xv0; aT0.y += gt1 * xv0;
                    aM0.z += gm2 * xv0; aT0.z += gt2 * xv0;
                    aM0.w += gm3 * xv0; aT0.w += gt3 * xv0;
                    aM1.x += gm0 * xv1; aT1.x += gt0 * xv1;
                    aM1.y += gm1 * xv1; aT1.y += gt1 * xv1;
                    aM1.z += gm2 * xv1; aT1.z += gt2 * xv1;
                    aM1.w += gm3 * xv1; aT1.w += gt3 * xv1;
                    if ((l & 3) == 3) __builtin_amdgcn_sched_barrier(0);
                }
                const int cell = (bp * 6 + sq) * NYR_;
                h4 pm0, pm1;
                pm0.x=(_Float16)aM0.x; pm0.y=(_Float16)aM0.y; pm0.z=(_Float16)aM0.z; pm0.w=(_Float16)aM0.w;
                pm1.x=(_Float16)aM1.x; pm1.y=(_Float16)aM1.y; pm1.z=(_Float16)aM1.z; pm1.w=(_Float16)aM1.w;
                Y4[(cell + tt) * 2 + 0] = pm0;
                Y4[(cell + tt) * 2 + 1] = pm1;
                if (tt < 23) {
                    h4 pt0, pt1;
                    pt0.x=(_Float16)aT0.x; pt0.y=(_Float16)aT0.y; pt0.z=(_Float16)aT0.z; pt0.w=(_Float16)aT0.w;
                    pt1.x=(_Float16)aT1.x; pt1.y=(_Float16)aT1.y; pt1.z=(_Float16)aT1.z; pt1.w=(_Float16)aT1.w;
                    Y4[(cell + 256 + tt) * 2 + 0] = pt0;
                    Y4[(cell + 256 + tt) * 2 + 1] = pt1;
                }
            }
        } else {
            #pragma unroll 1
            for (int sq = 0; sq < 6; ++sq) {
                float4 aM0, aM1;
                aM0.x=aM0.y=aM0.z=aM0.w=0.f; aM1=aM0;
                #pragma unroll
                for (int l = 0; l < L_; ++l) {
                    h2 f01; f01.x = (_Float16)FR[l]; f01.y = (_Float16)FG[l];
                    h2 f23; f23.x = (_Float16)FB[l]; f23.y = (_Float16)FC[l];
                    const int idx = tt - l;      // tt >= 64 -> always >= 41
                    const int ab = (4 * sq) * AP_ + idx;
                    const h4 p0 = A4[ab], p1 = A4[ab + AP_], p2 = A4[ab + 2 * AP_], p3 = A4[ab + 3 * AP_];
                    const h2 xq = XT2[(idx * XTP_ + l) * 2 + bp];
                    const float g0 = fdot2(h2{p0.x,p0.y}, f01, fdot2(h2{p0.z,p0.w}, f23, 0.f));
                    const float g1 = fdot2(h2{p1.x,p1.y}, f01, fdot2(h2{p1.z,p1.w}, f23, 0.f));
                    const float g2 = fdot2(h2{p2.x,p2.y}, f01, fdot2(h2{p2.z,p2.w}, f23, 0.f));
                    const float g3 = fdot2(h2{p3.x,p3.y}, f01, fdot2(h2{p3.z,p3.w}, f23, 0.f));
                    const float xv0 = (float)xq.x, xv1 = (float)xq.y;
                    aM0.x += g0 * xv0; aM1.x += g0 * xv1;
                    aM0.y += g1 * xv0; aM1.y += g1 * xv1;
                    aM0.z += g2 * xv0; aM1.z += g2 * xv1;
                    aM0.w += g3 * xv0; aM1.w += g3 * xv1;
                    if ((l & 3) == 3) __builtin_amdgcn_sched_barrier(0);
                }
                const int cell = (bp * 6 + sq) * NYR_;
                h4 pm0, pm1;
                pm0.x=(_Float16)aM0.x; pm0.y=(_Float16)aM0.y; pm0.z=(_Float16)aM0.z; pm0.w=(_Float16)aM0.w;
                pm1.x=(_Float16)aM1.x; pm1.y=(_Float16)aM1.y; pm1.z=(_Float16)aM1.z; pm1.w=(_Float16)aM1.w;
                Y4[(cell + tt) * 2 + 0] = pm0;
                Y4[(cell + tt) * 2 + 1] = pm1;
            }
        }
    }
    __syncthreads();

    // ---- Phase B: one b-pair per thread (bp = th), two l-halves.
    float vmax = 0.f;
    phaseB_half<0>(A4, Y8, out, tt, th, m, vmax);
    phaseB_half<1>(A4, Y8, out, tt, th, m, vmax);

    #pragma unroll
    for (int off = 32; off > 0; off >>= 1)
        vmax = fmaxf(vmax, __shfl_xor(vmax, off, 64));
    if ((t & 63) == 0) wmax[t >> 6] = vmax;
    __syncthreads();
    if (t == 0) {
        float v = wmax[0];
        #pragma unroll
        for (int w = 1; w < 8; ++w) v = fmaxf(v, wmax[w]);
        bmax_out[m] = v;
    }
}

// Normalize; each block re-reduces the 256 per-block maxes itself.
__global__ __launch_bounds__(256) void cassi_norm(float* __restrict__ out,
                                                  const float* __restrict__ bmax)
{
    __shared__ float wm[4];
    const int t = threadIdx.x;
    float v = bmax[t];
    #pragma unroll
    for (int off = 32; off > 0; off >>= 1)
        v = fmaxf(v, __shfl_xor(v, off, 64));
    if ((t & 63) == 0) wm[t >> 6] = v;
    __syncthreads();
    const float inv = 1.f / fmaxf(fmaxf(wm[0], wm[1]), fmaxf(wm[2], wm[3]));
    const int i = (blockIdx.x * 256 + t) * 4;
    float4 q = *reinterpret_cast<float4*>(out + i);
    q.x *= inv; q.y *= inv; q.z *= inv; q.w *= inv;
    *reinterpret_cast<float4*>(out + i) = q;
}

extern "C" void kernel_launch(void* const* d_in, const int* in_sizes, int n_in,
                              void* d_out, int out_size, void* d_ws, size_t ws_size,
                              hipStream_t stream) {
    const float* x  = (const float*)d_in[0];
    const float* wr = (const float*)d_in[1];
    const float* wg = (const float*)d_in[2];
    const float* wb = (const float*)d_in[3];
    const float* wc = (const float*)d_in[4];
    float* out  = (float*)d_out;
    float* bmax = (float*)d_ws;          // 256 per-block maxes

    cassi_fused<<<M_, 512, 0, stream>>>(x, wr, wg, wb, wc, out, bmax);
    const int n4blocks = (B_ * M_ * N_ * L_) / 4 / 256;     // 6144, exact
    cassi_norm<<<n4blocks, 256, 0, stream>>>(out, bmax);
}